// Round 6
// baseline (733.411 us; speedup 1.0000x reference)
//
#include <hip/hip_runtime.h>
#include <math.h>

#define L_SEQ 512
#define BATCH 128
#define DIN   128
#define HID   512
#define NOUT  5

typedef unsigned short u16;
typedef unsigned int   u32;
typedef __attribute__((ext_vector_type(8))) short short8;
typedef __attribute__((ext_vector_type(4))) float f32x4;

// ---------------------------------------------------------------------------
// bf16 split helpers (RNE).
// ---------------------------------------------------------------------------
__device__ __forceinline__ u16 f2bf(float x) {
  u32 u = __float_as_uint(x);
  return (u16)((u + 0x7fffu + ((u >> 16) & 1u)) >> 16);
}
__device__ __forceinline__ float bf2f(u16 s) {
  return __uint_as_float(((u32)s) << 16);
}
__device__ __forceinline__ void gload16(const void* g, void* l) {
  __builtin_amdgcn_global_load_lds(
      (const __attribute__((address_space(1))) u32*)g,
      (__attribute__((address_space(3))) u32*)l, 16, 0, 0);
}

// ---------------------------------------------------------------------------
// Packed-split bf16 GEMM: C[M,N] = A2[M,K']*B2[N,K']^T, plain bf16 MFMA.
// A2 = [Ah|Ah|Al], B2 = [Wh|Wl|Wh] along K' => exactly Ah*Wh + Ah*Wl + Al*Wh.
// Tile 256x256, BK=32, 8 waves (2Mx4N, per-wave 128x64), 4-deep LDS ring
// (4 x 32KB = 128KB), stage lead = 3 K-steps, vmcnt(8) once per K-step.
//
// Ledger (per wave, 4 gloads/step, issued as A(2) in ph1 + B(2) in ph2):
//   prologue: stage steps 0,1,2 (12 loads) -> vmcnt(8) drains step 0.
//   step s stages step s+3 into buf (s+3)&3 = (s-1)&3, whose reads all
//   retired at step s-1's final barrier  -> WAR safe.
//   end of step s: vmcnt(8) leaves exactly {s+2,s+3} pending -> step s+1
//   resident before its ph1 ds_reads     -> RAW safe.
//   tail: s+3>=NT stages skipped; waits decay 8 -> 4 -> 0.
// Swizzle: 16B slot ^= (row>>1)&3 within each 64B row (R3/R5-verified, 0
// bank conflicts). Fragment layout / epilogue identical to R3-verified code.
// ---------------------------------------------------------------------------
#define RBUF 16384u   // u16 per ring buffer (32KB): A at 0, B at 8192

__global__ __launch_bounds__(512, 2)
void gemm_packed(const u16* __restrict__ A, const u16* __restrict__ B,
                 float* __restrict__ C, int N, int K, int NBX) {
  __shared__ u16 lds[4 * RBUF];   // 128 KB

  const int NT = K >> 5;
  const int nwg = gridDim.x;
  int bid = blockIdx.x;
  { const int cpx = nwg >> 3;     // all grids here are %8 == 0
    bid = (bid & 7) * cpx + (bid >> 3); }
  const int bx = bid % NBX, by = bid / NBX;

  const int tid = threadIdx.x;
  const int w = tid >> 6, lane = tid & 63;
  const int wm = w >> 2, wn = w & 3;   // 2M x 4N wave grid

  // ---- staging addressing: round g covers rows [g*128, g*128+128) ----
  const int rs = lane >> 2, sl = lane & 3;
  const int r0 = w * 16 + rs, r1 = 128 + r0;
  const u16* pA0 = A + (size_t)(by * 256 + r0) * K + ((sl ^ ((r0 >> 1) & 3)) * 8);
  const u16* pA1 = A + (size_t)(by * 256 + r1) * K + ((sl ^ ((r1 >> 1) & 3)) * 8);
  const u16* pB0 = B + (size_t)(bx * 256 + r0) * K + ((sl ^ ((r0 >> 1) & 3)) * 8);
  const u16* pB1 = B + (size_t)(bx * 256 + r1) * K + ((sl ^ ((r1 >> 1) & 3)) * 8);
  const int dA0 = w * 512,        dA1 = 4096 + w * 512;    // wave-uniform
  const int dB0 = 8192 + w * 512, dB1 = 12288 + w * 512;

#define STAGE_A(ts) do { const int _bb = ((ts) & 3) * (int)RBUF, _ks = (ts) << 5; \
    gload16(pA0 + _ks, &lds[_bb + dA0]); \
    gload16(pA1 + _ks, &lds[_bb + dA1]); } while (0)
#define STAGE_B(ts) do { const int _bb = ((ts) & 3) * (int)RBUF, _ks = (ts) << 5; \
    gload16(pB0 + _ks, &lds[_bb + dB0]); \
    gload16(pB1 + _ks, &lds[_bb + dB1]); } while (0)

  // ---- fragment read offsets (u16 idx, swizzle-matched) ----
  const int frow = lane & 15, fsl = lane >> 4;
  int offA[8], offB[4];
#pragma unroll
  for (int i = 0; i < 8; ++i) {
    const int ra = wm * 128 + i * 16 + frow;
    offA[i] = ra * 32 + ((fsl ^ ((ra >> 1) & 3)) * 8);
  }
#pragma unroll
  for (int j = 0; j < 4; ++j) {
    const int rb = wn * 64 + j * 16 + frow;
    offB[j] = 8192 + rb * 32 + ((fsl ^ ((rb >> 1) & 3)) * 8);
  }

  f32x4 acc[8][4];
#pragma unroll
  for (int i = 0; i < 8; ++i)
#pragma unroll
    for (int j = 0; j < 4; ++j)
#pragma unroll
      for (int q = 0; q < 4; ++q) acc[i][j][q] = 0.f;

  // prologue: stage steps 0,1,2; drain step 0 (12 issued, keep 8)
  STAGE_A(0); STAGE_B(0); STAGE_A(1); STAGE_B(1); STAGE_A(2); STAGE_B(2);
  asm volatile("s_waitcnt vmcnt(8)" ::: "memory");
  __builtin_amdgcn_s_barrier();

  for (int s = 0; s < NT; ++s) {
    const int bb = (s & 3) * (int)RBUF;
    const int ts = s + 3;
    const bool st = ts < NT;

    // -------- phase 1: B frags + A rows 0..3, stage A(s+3) --------
    short8 bfr[4], afr[4];
#pragma unroll
    for (int j = 0; j < 4; ++j) bfr[j] = *(const short8*)&lds[bb + offB[j]];
#pragma unroll
    for (int i = 0; i < 4; ++i) afr[i] = *(const short8*)&lds[bb + offA[i]];
    if (st) STAGE_A(ts);
    __builtin_amdgcn_s_barrier();
    asm volatile("s_waitcnt lgkmcnt(0)" ::: "memory");
    __builtin_amdgcn_sched_barrier(0);
    __builtin_amdgcn_s_setprio(1);
#pragma unroll
    for (int i = 0; i < 4; ++i)
#pragma unroll
      for (int j = 0; j < 4; ++j)
        acc[i][j] = __builtin_amdgcn_mfma_f32_16x16x32_bf16(afr[i], bfr[j], acc[i][j], 0, 0, 0);
    __builtin_amdgcn_s_setprio(0);
    __builtin_amdgcn_s_barrier();

    // -------- phase 2: A rows 4..7 (B reused), stage B(s+3) --------
#pragma unroll
    for (int i = 0; i < 4; ++i) afr[i] = *(const short8*)&lds[bb + offA[4 + i]];
    if (st) STAGE_B(ts);
    __builtin_amdgcn_s_barrier();
    asm volatile("s_waitcnt lgkmcnt(0)" ::: "memory");
    __builtin_amdgcn_sched_barrier(0);
    __builtin_amdgcn_s_setprio(1);
#pragma unroll
    for (int i = 0; i < 4; ++i)
#pragma unroll
      for (int j = 0; j < 4; ++j)
        acc[4 + i][j] = __builtin_amdgcn_mfma_f32_16x16x32_bf16(afr[i], bfr[j], acc[4 + i][j], 0, 0, 0);
    __builtin_amdgcn_s_setprio(0);
    if (s + 3 < NT)      { asm volatile("s_waitcnt vmcnt(8)" ::: "memory"); }
    else if (s + 2 < NT) { asm volatile("s_waitcnt vmcnt(4)" ::: "memory"); }
    else if (s + 1 < NT) { asm volatile("s_waitcnt vmcnt(0)" ::: "memory"); }
    __builtin_amdgcn_s_barrier();
  }
#undef STAGE_A
#undef STAGE_B

  // epilogue: C/D layout col=lane&15, row=(lane>>4)*4+q  [R3-verified]
  const int crow0 = by * 256 + wm * 128 + (lane >> 4) * 4;
  const int ccol0 = bx * 256 + wn * 64 + (lane & 15);
#pragma unroll
  for (int i = 0; i < 8; ++i)
#pragma unroll
    for (int j = 0; j < 4; ++j) {
      float* cp = C + (size_t)(crow0 + i * 16) * N + ccol0 + j * 16;
#pragma unroll
      for (int q = 0; q < 4; ++q) cp[(size_t)q * N] = acc[i][j][q];
    }
}

// ---------------------------------------------------------------------------
// one-time packing kernels
// ---------------------------------------------------------------------------
// x[65536][128] f32 -> x2[65536][384] bf16 = [xh | xh | xl]
__global__ __launch_bounds__(256)
void pack_x(const float* __restrict__ x, u16* __restrict__ x2, int n) {
  const int i = blockIdx.x * 256 + threadIdx.x;
  if (i >= n) return;
  const int row = i >> 7, k = i & 127;
  const float v = x[i];
  const u16 h = f2bf(v), l = f2bf(v - bf2f(h));
  u16* r = x2 + (size_t)row * 384;
  r[k] = h; r[128 + k] = h; r[256 + k] = l;
}

// W[K][N] f32 -> W2[N][3K] bf16 = [Wh | Wl | Wh] (transposed, K-contig)
__global__ __launch_bounds__(256)
void pack_w(const float* __restrict__ W, u16* __restrict__ W2, int K, int N) {
  const int idx = blockIdx.x * 256 + threadIdx.x;
  if (idx >= K * N) return;
  const int k = idx / N, n = idx - k * N;
  const float v = W[idx];
  const u16 h = f2bf(v), l = f2bf(v - bf2f(h));
  u16* r = W2 + (size_t)n * (3 * K);
  r[k] = h; r[K + k] = l; r[2 * K + k] = h;
}

// ---------------------------------------------------------------------------
__device__ __forceinline__ float sig(float x) { return 1.f / (1.f + __expf(-x)); }

// Layer-0 scan over one chunk; emits h1 packed as [Ah|Ah|Al] rows of h1_2.
__global__ __launch_bounds__(256)
void sru_scan0_chunk(const float* __restrict__ U, const float* __restrict__ v,
                     const float* __restrict__ bias, u16* __restrict__ h1_2,
                     float* __restrict__ cstate, int Tc, int init) {
  const int j = blockIdx.x * 256 + threadIdx.x;
  const int b = j >> 9, h = j & (HID - 1);
  const float vf = v[h], vr = v[HID + h];
  const float bf = bias[h], br = bias[HID + h];

  const float* p = U + (size_t)b * (3 * HID) + h;
  const size_t sT = (size_t)BATCH * 3 * HID;
  u16* ph = h1_2 + (size_t)b * 1536 + h;
  const size_t sH = (size_t)BATCH * 1536;

  float c = init ? 0.f : cstate[j];
  float cu[12];
#pragma unroll
  for (int q = 0; q < 4; ++q) {
    cu[3 * q + 0] = p[q * sT];
    cu[3 * q + 1] = p[q * sT + HID];
    cu[3 * q + 2] = p[q * sT + 2 * HID];
  }
  const int NG = Tc >> 2;
  for (int g = 0; g < NG; ++g) {
    float nx[12];
    const bool has = (g + 1 < NG);
    if (has) {
      const float* pn = p + 4 * sT;
#pragma unroll
      for (int q = 0; q < 4; ++q) {
        nx[3 * q + 0] = pn[q * sT];
        nx[3 * q + 1] = pn[q * sT + HID];
        nx[3 * q + 2] = pn[q * sT + 2 * HID];
      }
    }
#pragma unroll
    for (int q = 0; q < 4; ++q) {
      const float u0 = cu[3 * q], u1 = cu[3 * q + 1], u2 = cu[3 * q + 2];
      const float f = sig(u1 + vf * c + bf);
      const float r = sig(u2 + vr * c + br);
      c = f * c + (1.f - f) * u0;
      const float hv = r * c;
      const u16 hh = f2bf(hv);
      const u16 hl = f2bf(hv - bf2f(hh));
      u16* pr = ph + (size_t)(g * 4 + q) * sH;
      pr[0] = hh; pr[512] = hh; pr[1024] = hl;
    }
    p += 4 * sT;
    if (has) {
#pragma unroll
      for (int i = 0; i < 12; ++i) cu[i] = nx[i];
    }
  }
  cstate[j] = c;
}

// Layer-1 scan: only u0/u1 needed except the single global last step.
__global__ __launch_bounds__(256)
void sru_scan1_chunk(const float* __restrict__ U, const float* __restrict__ v,
                     const float* __restrict__ bias, float* __restrict__ cstate,
                     float* __restrict__ hlast, int Tc, int lastT, int init) {
  const int j = blockIdx.x * 256 + threadIdx.x;
  const int b = j >> 9, h = j & (HID - 1);
  const float vf = v[h], vr = v[HID + h];
  const float bf = bias[h], br = bias[HID + h];

  const float* p = U + (size_t)b * (3 * HID) + h;
  const size_t sT = (size_t)BATCH * 3 * HID;

  float c = init ? 0.f : cstate[j];
  float cu[8];
#pragma unroll
  for (int q = 0; q < 4; ++q) {
    cu[2 * q + 0] = p[q * sT];
    cu[2 * q + 1] = p[q * sT + HID];
  }
  const int NG = Tc >> 2;
  for (int g = 0; g < NG; ++g) {
    float nx[8];
    const bool has = (g + 1 < NG);
    if (has) {
      const float* pn = p + 4 * sT;
#pragma unroll
      for (int q = 0; q < 4; ++q) {
        nx[2 * q + 0] = pn[q * sT];
        nx[2 * q + 1] = pn[q * sT + HID];
      }
    }
#pragma unroll
    for (int q = 0; q < 4; ++q) {
      const float u0 = cu[2 * q], u1 = cu[2 * q + 1];
      const float f = sig(u1 + vf * c + bf);
      const float cn = f * c + (1.f - f) * u0;
      if (g * 4 + q == lastT) {
        const float u2 = p[q * sT + 2 * HID];
        const float r = sig(u2 + vr * c + br);
        hlast[j] = r * cn;
      }
      c = cn;
    }
    p += 4 * sT;
    if (has) {
#pragma unroll
      for (int i = 0; i < 8; ++i) cu[i] = nx[i];
    }
  }
  cstate[j] = c;
}

// ---------------------------------------------------------------------------
__global__ __launch_bounds__(256)
void fc_head(const float* __restrict__ h, const float* __restrict__ w,
             const float* __restrict__ bias, float* __restrict__ out) {
  const int gid = blockIdx.x * 256 + threadIdx.x;
  const int wv = gid >> 6, lane = threadIdx.x & 63;
  if (wv >= BATCH * NOUT) return;
  const int b = wv / NOUT, o = wv % NOUT;
  float s = 0.f;
#pragma unroll
  for (int k = lane; k < HID; k += 64)
    s += h[(size_t)b * HID + k] * w[(size_t)o * HID + k];
#pragma unroll
  for (int off = 32; off > 0; off >>= 1) s += __shfl_down(s, off);
  if (lane == 0) out[(size_t)b * NOUT + o] = s + bias[o];
}

// ---------------------------------------------------------------------------
extern "C" void kernel_launch(void* const* d_in, const int* in_sizes, int n_in,
                              void* d_out, int out_size, void* d_ws, size_t ws_size,
                              hipStream_t stream) {
  const float* x   = (const float*)d_in[0];
  const float* W0  = (const float*)d_in[1];
  const float* v0  = (const float*)d_in[2];
  const float* b0  = (const float*)d_in[3];
  const float* W1  = (const float*)d_in[4];
  const float* v1  = (const float*)d_in[5];
  const float* b1  = (const float*)d_in[6];
  const float* fcw = (const float*)d_in[7];
  const float* fcb = (const float*)d_in[8];
  float* out = (float*)d_out;

  const size_t nXel = (size_t)L_SEQ * BATCH * DIN;   // 8.39M elements
  const size_t nX2  = (size_t)L_SEQ * BATCH * 384;   // packed x, u16
  const size_t nW02 = (size_t)1536 * 384;            // packed W0^T, u16
  const size_t nW12 = (size_t)1536 * 1536;           // packed W1^T, u16

  // largest Tc that fits (Tc=128 -> ~208 MB; 269 MB proven available in R2)
  int Tc = 128;
  for (;;) {
    size_t f32e = (size_t)Tc * BATCH * 3 * HID + 3 * (size_t)BATCH * HID;
    size_t u16e = nX2 + (size_t)Tc * BATCH * 1536 + nW02 + nW12;
    if (f32e * 4 + u16e * 2 + 1024 <= ws_size || Tc <= 8) break;
    Tc >>= 1;
  }
  const int NC = L_SEQ / Tc;
  const int Mc = Tc * BATCH;

  float* U0c = (float*)d_ws;                    // Mc*1536 f32 (both layers)
  float* c0  = U0c + (size_t)Mc * 1536;
  float* c1  = c0 + (size_t)BATCH * HID;
  float* h2  = c1 + (size_t)BATCH * HID;
  u16* x2   = (u16*)(h2 + (size_t)BATCH * HID); // [65536][384]
  u16* h1_2 = x2 + nX2;                         // [Mc][1536]
  u16* w0_2 = h1_2 + (size_t)Mc * 1536;         // [1536][384]
  u16* w1_2 = w0_2 + nW02;                      // [1536][1536]

  const int scan_grid = (BATCH * HID) / 256;
  const int fc_grid = (BATCH * NOUT * 64 + 255) / 256;
  const int grid_full = (Mc / 256) * 6;   // N=1536 panels
  const int grid_01   = (Mc / 256) * 4;   // u0,u1 panels only

  pack_x<<<(int)(nXel + 255) / 256, 256, 0, stream>>>(x, x2, (int)nXel);
  pack_w<<<(int)((size_t)DIN * 1536 + 255) / 256, 256, 0, stream>>>(W0, w0_2, DIN, 1536);
  pack_w<<<(int)((size_t)HID * 1536 + 255) / 256, 256, 0, stream>>>(W1, w1_2, HID, 1536);

  for (int ch = 0; ch < NC; ++ch) {
    const bool last = (ch == NC - 1);
    gemm_packed<<<grid_full, 512, 0, stream>>>(
        x2 + (size_t)ch * Tc * BATCH * 384, w0_2, U0c, 1536, 384, 6);
    sru_scan0_chunk<<<scan_grid, 256, 0, stream>>>(U0c, v0, b0, h1_2, c0, Tc, ch == 0);
    gemm_packed<<<last ? grid_full : grid_01, 512, 0, stream>>>(
        h1_2, w1_2, U0c, 1536, 1536, last ? 6 : 4);
    sru_scan1_chunk<<<scan_grid, 256, 0, stream>>>(
        U0c, v1, b1, c1, h2, Tc, last ? Tc - 1 : -1, ch == 0);
  }
  fc_head<<<fc_grid, 256, 0, stream>>>(h2, fcw, fcb, out);
}

// Round 10
// 628.779 us; speedup vs baseline: 1.1664x; 1.1664x over previous
//
#include <hip/hip_runtime.h>
#include <math.h>

#define L_SEQ 512
#define BATCH 128
#define DIN   128
#define HID   512
#define NOUT  5
#define NSTR  1536   // C row stride (u0|u1|u2 panels)

typedef unsigned short u16;
typedef unsigned int   u32;
typedef __attribute__((ext_vector_type(8))) short short8;
typedef __attribute__((ext_vector_type(4))) float f32x4;

// ---------------------------------------------------------------------------
// bf16 split helpers (RNE).
// ---------------------------------------------------------------------------
__device__ __forceinline__ u16 f2bf(float x) {
  u32 u = __float_as_uint(x);
  return (u16)((u + 0x7fffu + ((u >> 16) & 1u)) >> 16);
}
__device__ __forceinline__ float bf2f(u16 s) {
  return __uint_as_float(((u32)s) << 16);
}
__device__ __forceinline__ void gload16(const void* g, void* l) {
  __builtin_amdgcn_global_load_lds(
      (const __attribute__((address_space(1))) u32*)g,
      (__attribute__((address_space(3))) u32*)l, 16, 0, 0);
}

// ---------------------------------------------------------------------------
// R3-verified split-bf16 MFMA GEMM body (888 TF, MfmaUtil 37%, 0 bank
// conflicts, absmax 7.6e-6): 128x128 tile, BK=32, 4 waves, 2-barrier loop,
// multi-block/CU for implicit cross-block overlap (m114). Reverted verbatim
// from R3 after three phase-schedule variants all regressed (877/829/707 TF).
// Dual-role kernel: blocks [0,nblk0) run args g0 (GEMM1 of chunk ch),
// blocks [nblk0,..) run g1 (GEMM0 of chunk ch+1) — absorbs the small-K
// GEMM0 into GEMM1's wall time.
// ---------------------------------------------------------------------------
struct GArgs {
  const u16* Ah; const u16* Al;   // A hi/lo  [M][K]
  const u16* Bh; const u16* Bl;   // B^T hi/lo [N][K]
  float* C;                       // [M][NSTR]
  int K;                          // 512 (GEMM1) or 128 (GEMM0)
  int NBX;                        // 128-col panels to compute (8 or 12)
};

__global__ __launch_bounds__(256, 2)
void gemm_dual(GArgs g0, int nblk0, GArgs g1) {
  const bool first = (int)blockIdx.x < nblk0;
  const GArgs g = first ? g0 : g1;
  const int bid = first ? (int)blockIdx.x : (int)blockIdx.x - nblk0;
  const int K = g.K;

  __shared__ u16 sAh[4096], sAl[4096], sBh[4096], sBl[4096];

  const int bx = bid % g.NBX;
  const int by = bid / g.NBX;
  const int tid = threadIdx.x;
  const int wid = tid >> 6, lane = tid & 63;

  // staging: thread covers 16B = 8 u16; round r covers tile rows [r*64, +64)
  const int srow = tid >> 2;
  const int sw = (tid & 3) ^ ((srow >> 1) & 3);   // swizzled 16B slot
  const size_t aoff0 = (size_t)(by * 128 + srow) * K + sw * 8;
  const size_t aoff1 = aoff0 + (size_t)64 * K;
  const size_t boff0 = (size_t)(bx * 128 + srow) * K + sw * 8;
  const size_t boff1 = boff0 + (size_t)64 * K;
  const int d0 = wid * 512;          // LDS dest (u16 idx), wave-uniform
  const int d1 = 2048 + wid * 512;

  // fragment read offsets (u16 idx), swizzle-matched
  const int wm = wid >> 1, wn = wid & 1;
  const int frow = lane & 15, fsl = lane >> 4;
  int offA[4], offB[4];
#pragma unroll
  for (int i = 0; i < 4; ++i) {
    const int ra = wm * 64 + i * 16 + frow;
    offA[i] = ra * 32 + ((fsl ^ ((ra >> 1) & 3)) * 8);
    const int rb = wn * 64 + i * 16 + frow;
    offB[i] = rb * 32 + ((fsl ^ ((rb >> 1) & 3)) * 8);
  }

  f32x4 acc[4][4];
#pragma unroll
  for (int i = 0; i < 4; ++i)
#pragma unroll
    for (int j = 0; j < 4; ++j)
#pragma unroll
      for (int q = 0; q < 4; ++q) acc[i][j][q] = 0.f;

  for (int k0 = 0; k0 < K; k0 += 32) {
    __syncthreads();  // previous compute done before overwriting LDS
    gload16(g.Ah + aoff0 + k0, &sAh[d0]);
    gload16(g.Ah + aoff1 + k0, &sAh[d1]);
    gload16(g.Al + aoff0 + k0, &sAl[d0]);
    gload16(g.Al + aoff1 + k0, &sAl[d1]);
    gload16(g.Bh + boff0 + k0, &sBh[d0]);
    gload16(g.Bh + boff1 + k0, &sBh[d1]);
    gload16(g.Bl + boff0 + k0, &sBl[d0]);
    gload16(g.Bl + boff1 + k0, &sBl[d1]);
    __syncthreads();  // compiler drains vmcnt(0) before barrier

    short8 bh[4], bl[4];
#pragma unroll
    for (int j = 0; j < 4; ++j) {
      bh[j] = *(const short8*)&sBh[offB[j]];
      bl[j] = *(const short8*)&sBl[offB[j]];
    }
#pragma unroll
    for (int i = 0; i < 4; ++i) {
      const short8 ah = *(const short8*)&sAh[offA[i]];
      const short8 al = *(const short8*)&sAl[offA[i]];
#pragma unroll
      for (int j = 0; j < 4; ++j) {
        acc[i][j] = __builtin_amdgcn_mfma_f32_16x16x32_bf16(ah, bh[j], acc[i][j], 0, 0, 0);
        acc[i][j] = __builtin_amdgcn_mfma_f32_16x16x32_bf16(ah, bl[j], acc[i][j], 0, 0, 0);
        acc[i][j] = __builtin_amdgcn_mfma_f32_16x16x32_bf16(al, bh[j], acc[i][j], 0, 0, 0);
      }
    }
  }

  // epilogue: C/D layout col=lane&15, row=(lane>>4)*4+q  [R3-verified]
  const int crow0 = by * 128 + wm * 64 + (lane >> 4) * 4;
  const int ccol0 = bx * 128 + wn * 64 + (lane & 15);
#pragma unroll
  for (int i = 0; i < 4; ++i)
#pragma unroll
    for (int j = 0; j < 4; ++j) {
      float* cp = g.C + (size_t)(crow0 + i * 16) * NSTR + ccol0 + j * 16;
#pragma unroll
      for (int q = 0; q < 4; ++q) cp[(size_t)q * NSTR] = acc[i][j][q];
    }
}

// ---------------------------------------------------------------------------
// one-time input conversions
// ---------------------------------------------------------------------------
__global__ __launch_bounds__(256)
void split4_f32(const float* __restrict__ in, u16* __restrict__ hi,
                u16* __restrict__ lo, int n4) {
  const int i = blockIdx.x * 256 + threadIdx.x;
  if (i >= n4) return;
  const float4 v = ((const float4*)in)[i];
  u16 h0 = f2bf(v.x), h1 = f2bf(v.y), h2 = f2bf(v.z), h3 = f2bf(v.w);
  u16 l0 = f2bf(v.x - bf2f(h0)), l1 = f2bf(v.y - bf2f(h1));
  u16 l2 = f2bf(v.z - bf2f(h2)), l3 = f2bf(v.w - bf2f(h3));
  uint2 hp, lp;
  hp.x = (u32)h0 | ((u32)h1 << 16); hp.y = (u32)h2 | ((u32)h3 << 16);
  lp.x = (u32)l0 | ((u32)l1 << 16); lp.y = (u32)l2 | ((u32)l3 << 16);
  ((uint2*)hi)[i] = hp;
  ((uint2*)lo)[i] = lp;
}

// W[K][N] f32 -> WT hi/lo [N][K] bf16 (transposed: GEMM B-frags K-contig)
__global__ __launch_bounds__(256)
void split_w_t(const float* __restrict__ W, u16* __restrict__ Th,
               u16* __restrict__ Tl, int K, int N) {
  const int idx = blockIdx.x * 256 + threadIdx.x;
  if (idx >= K * N) return;
  const int k = idx / N, n = idx - k * N;
  const float x = W[idx];
  const u16 h = f2bf(x);
  Th[(size_t)n * K + k] = h;
  Tl[(size_t)n * K + k] = f2bf(x - bf2f(h));
}

// ---------------------------------------------------------------------------
__device__ __forceinline__ float sig(float x) { return 1.f / (1.f + __expf(-x)); }

// Layer-0 scan body: one thread per (b,h) chain over one chunk; emits h1 as
// separate hi/lo bf16 (GEMM1's A). Group-of-4 load pipeline.
__device__ __forceinline__
void scan0_body(int j, const float* __restrict__ U, const float* __restrict__ v,
                const float* __restrict__ bias, u16* __restrict__ h1h,
                u16* __restrict__ h1l, float* __restrict__ cstate, int Tc, int init) {
  const int b = j >> 9, h = j & (HID - 1);
  const float vf = v[h], vr = v[HID + h];
  const float bf = bias[h], br = bias[HID + h];

  const float* p = U + (size_t)b * NSTR + h;
  const size_t sT = (size_t)BATCH * NSTR;
  u16* ph = h1h + (size_t)b * HID + h;
  u16* pl = h1l + (size_t)b * HID + h;
  const size_t sH = (size_t)BATCH * HID;

  float c = init ? 0.f : cstate[j];
  float cu[12];
#pragma unroll
  for (int q = 0; q < 4; ++q) {
    cu[3 * q + 0] = p[q * sT];
    cu[3 * q + 1] = p[q * sT + HID];
    cu[3 * q + 2] = p[q * sT + 2 * HID];
  }
  const int NG = Tc >> 2;
  for (int g = 0; g < NG; ++g) {
    float nx[12];
    const bool has = (g + 1 < NG);
    if (has) {
      const float* pn = p + 4 * sT;
#pragma unroll
      for (int q = 0; q < 4; ++q) {
        nx[3 * q + 0] = pn[q * sT];
        nx[3 * q + 1] = pn[q * sT + HID];
        nx[3 * q + 2] = pn[q * sT + 2 * HID];
      }
    }
#pragma unroll
    for (int q = 0; q < 4; ++q) {
      const float u0 = cu[3 * q], u1 = cu[3 * q + 1], u2 = cu[3 * q + 2];
      const float f = sig(u1 + vf * c + bf);
      const float r = sig(u2 + vr * c + br);
      c = f * c + (1.f - f) * u0;
      const float hv = r * c;
      const u16 hh = f2bf(hv);
      ph[(size_t)(g * 4 + q) * sH] = hh;
      pl[(size_t)(g * 4 + q) * sH] = f2bf(hv - bf2f(hh));
    }
    p += 4 * sT;
    if (has) {
#pragma unroll
      for (int i = 0; i < 12; ++i) cu[i] = nx[i];
    }
  }
  cstate[j] = c;
}

// Layer-1 scan body: only u0/u1 needed except the single global last step.
__device__ __forceinline__
void scan1_body(int j, const float* __restrict__ U, const float* __restrict__ v,
                const float* __restrict__ bias, float* __restrict__ cstate,
                float* __restrict__ hlast, int Tc, int lastT, int init) {
  const int b = j >> 9, h = j & (HID - 1);
  const float vf = v[h], vr = v[HID + h];
  const float bf = bias[h], br = bias[HID + h];

  const float* p = U + (size_t)b * NSTR + h;
  const size_t sT = (size_t)BATCH * NSTR;

  float c = init ? 0.f : cstate[j];
  float cu[8];
#pragma unroll
  for (int q = 0; q < 4; ++q) {
    cu[2 * q + 0] = p[q * sT];
    cu[2 * q + 1] = p[q * sT + HID];
  }
  const int NG = Tc >> 2;
  for (int g = 0; g < NG; ++g) {
    float nx[8];
    const bool has = (g + 1 < NG);
    if (has) {
      const float* pn = p + 4 * sT;
#pragma unroll
      for (int q = 0; q < 4; ++q) {
        nx[2 * q + 0] = pn[q * sT];
        nx[2 * q + 1] = pn[q * sT + HID];
      }
    }
#pragma unroll
    for (int q = 0; q < 4; ++q) {
      const float u0 = cu[2 * q], u1 = cu[2 * q + 1];
      const float f = sig(u1 + vf * c + bf);
      const float cn = f * c + (1.f - f) * u0;
      if (g * 4 + q == lastT) {            // uniform; true once per sequence
        const float u2 = p[q * sT + 2 * HID];
        const float r = sig(u2 + vr * c + br);
        hlast[j] = r * cn;
      }
      c = cn;
    }
    p += 4 * sT;
    if (has) {
#pragma unroll
      for (int i = 0; i < 8; ++i) cu[i] = nx[i];
    }
  }
  cstate[j] = c;
}

// standalone layer-0 scan (chunk 0 only)
__global__ __launch_bounds__(256)
void sru_scan0(const float* __restrict__ U, const float* __restrict__ v,
               const float* __restrict__ bias, u16* __restrict__ h1h,
               u16* __restrict__ h1l, float* __restrict__ cstate, int Tc, int init) {
  scan0_body(blockIdx.x * 256 + threadIdx.x, U, v, bias, h1h, h1l, cstate, Tc, init);
}

// merged: blocks [0,256) = scan1(ch), blocks [256,512) = scan0(ch+1)
__global__ __launch_bounds__(256)
void scan_dual(const float* __restrict__ U1, const float* __restrict__ v1,
               const float* __restrict__ b1, float* __restrict__ c1,
               float* __restrict__ h2, int lastT, int init1,
               const float* __restrict__ U0n, const float* __restrict__ v0,
               const float* __restrict__ b0, u16* __restrict__ h1h,
               u16* __restrict__ h1l, float* __restrict__ c0, int Tc) {
  const int nb1 = (BATCH * HID) / 256;  // 256
  if ((int)blockIdx.x < nb1) {
    scan1_body(blockIdx.x * 256 + threadIdx.x, U1, v1, b1, c1, h2, Tc, lastT, init1);
  } else {
    scan0_body((blockIdx.x - nb1) * 256 + threadIdx.x, U0n, v0, b0, h1h, h1l, c0, Tc, 0);
  }
}

// ---------------------------------------------------------------------------
__global__ __launch_bounds__(256)
void fc_head(const float* __restrict__ h, const float* __restrict__ w,
             const float* __restrict__ bias, float* __restrict__ out) {
  const int gid = blockIdx.x * 256 + threadIdx.x;
  const int wv = gid >> 6, lane = threadIdx.x & 63;
  if (wv >= BATCH * NOUT) return;
  const int b = wv / NOUT, o = wv % NOUT;
  float s = 0.f;
#pragma unroll
  for (int k = lane; k < HID; k += 64)
    s += h[(size_t)b * HID + k] * w[(size_t)o * HID + k];
#pragma unroll
  for (int off = 32; off > 0; off >>= 1) s += __shfl_down(s, off);
  if (lane == 0) out[(size_t)b * NOUT + o] = s + bias[o];
}

// ---------------------------------------------------------------------------
extern "C" void kernel_launch(void* const* d_in, const int* in_sizes, int n_in,
                              void* d_out, int out_size, void* d_ws, size_t ws_size,
                              hipStream_t stream) {
  const float* x   = (const float*)d_in[0];
  const float* W0  = (const float*)d_in[1];
  const float* v0  = (const float*)d_in[2];
  const float* b0  = (const float*)d_in[3];
  const float* W1  = (const float*)d_in[4];
  const float* v1  = (const float*)d_in[5];
  const float* b1  = (const float*)d_in[6];
  const float* fcw = (const float*)d_in[7];
  const float* fcb = (const float*)d_in[8];
  float* out = (float*)d_out;

  const size_t nX  = (size_t)L_SEQ * BATCH * DIN;   // 8.39M
  const size_t nW0 = (size_t)DIN * NSTR;
  const size_t nW1 = (size_t)HID * NSTR;

  // largest Tc that fits: footprint(Tc) = 3*U(Tc) f32 + states + u16 arrays.
  // Tc=64 -> ~223 MB (<= 236 MB proven available in R2).
  int Tc = 64;
  for (;;) {
    size_t f32e = 3 * (size_t)Tc * BATCH * NSTR + 3 * (size_t)BATCH * HID;
    size_t u16e = 2 * nX + 4 * (size_t)Tc * BATCH * HID + 2 * nW0 + 2 * nW1;
    if (f32e * 4 + u16e * 2 + 1024 <= ws_size || Tc <= 8) break;
    Tc >>= 1;
  }
  const int NC = L_SEQ / Tc;
  const int Mc = Tc * BATCH;

  float* U1c   = (float*)d_ws;                      // [Mc][1536]
  float* U0a   = U1c + (size_t)Mc * NSTR;           // ping
  float* U0b   = U0a + (size_t)Mc * NSTR;           // pong
  float* c0    = U0b + (size_t)Mc * NSTR;
  float* c1    = c0 + (size_t)BATCH * HID;
  float* h2    = c1 + (size_t)BATCH * HID;
  u16* xs_h    = (u16*)(h2 + (size_t)BATCH * HID);
  u16* xs_l    = xs_h + nX;
  u16* h1h_a   = xs_l + nX;                         // [Mc][512] ping
  u16* h1l_a   = h1h_a + (size_t)Mc * HID;
  u16* h1h_b   = h1l_a + (size_t)Mc * HID;          // pong
  u16* h1l_b   = h1h_b + (size_t)Mc * HID;
  u16* w0t_h   = h1l_b + (size_t)Mc * HID;
  u16* w0t_l   = w0t_h + nW0;
  u16* w1t_h   = w0t_l + nW0;
  u16* w1t_l   = w1t_h + nW1;

  float* U0[2]  = {U0a, U0b};
  u16* h1h[2]   = {h1h_a, h1h_b};
  u16* h1l[2]   = {h1l_a, h1l_b};

  const int rows   = Mc / 128;                      // by range (64 at Tc=64)
  const int fcGrid = (BATCH * NOUT * 64 + 255) / 256;

  // one-time conversions
  split4_f32<<<(int)(nX / 4 + 255) / 256, 256, 0, stream>>>(x, xs_h, xs_l, (int)(nX / 4));
  split_w_t<<<(int)(nW0 + 255) / 256, 256, 0, stream>>>(W0, w0t_h, w0t_l, DIN, NSTR);
  split_w_t<<<(int)(nW1 + 255) / 256, 256, 0, stream>>>(W1, w1t_h, w1t_l, HID, NSTR);

  // GEMM0 chunk 0 -> U0[0]; scan0 chunk 0
  {
    GArgs ga = {xs_h, xs_l, w0t_h, w0t_l, U0[0], DIN, 12};
    gemm_dual<<<rows * 12, 256, 0, stream>>>(ga, rows * 12, ga);
    sru_scan0<<<(BATCH * HID) / 256, 256, 0, stream>>>(U0[0], v0, b0,
                                                       h1h[0], h1l[0], c0, Tc, 1);
  }

  for (int ch = 0; ch < NC; ++ch) {
    const bool last = (ch == NC - 1);
    const int cur = ch & 1, nxt = cur ^ 1;
    const int nbx1 = last ? 12 : 8;                 // u2-skip on non-last chunks
    const int nb0 = rows * nbx1;

    GArgs g1 = {h1h[cur], h1l[cur], w1t_h, w1t_l, U1c, HID, nbx1};
    GArgs g0n = g1;
    int nb1 = 0;
    if (!last) {
      const size_t xoff = (size_t)(ch + 1) * Mc * DIN;
      g0n = GArgs{xs_h + xoff, xs_l + xoff, w0t_h, w0t_l, U0[nxt], DIN, 12};
      nb1 = rows * 12;
    }
    gemm_dual<<<nb0 + nb1, 256, 0, stream>>>(g1, nb0, g0n);

    scan_dual<<<last ? 256 : 512, 256, 0, stream>>>(
        U1c, v1, b1, c1, h2, last ? Tc - 1 : -1, ch == 0,
        U0[nxt], v0, b0, h1h[nxt], h1l[nxt], c0, Tc);
  }
  fc_head<<<fcGrid, 256, 0, stream>>>(h2, fcw, fcb, out);
}

// Round 11
// 604.005 us; speedup vs baseline: 1.2142x; 1.0410x over previous
//
#include <hip/hip_runtime.h>
#include <math.h>

#define L_SEQ 512
#define BATCH 128
#define DIN   128
#define HID   512
#define NOUT  5
#define NSTR  1536   // C row stride (u0|u1|u2 panels)

typedef unsigned short u16;
typedef unsigned int   u32;
typedef __attribute__((ext_vector_type(8))) short short8;
typedef __attribute__((ext_vector_type(4))) float f32x4;

// ---------------------------------------------------------------------------
// bf16 split helpers (RNE).
// ---------------------------------------------------------------------------
__device__ __forceinline__ u16 f2bf(float x) {
  u32 u = __float_as_uint(x);
  return (u16)((u + 0x7fffu + ((u >> 16) & 1u)) >> 16);
}
__device__ __forceinline__ float bf2f(u16 s) {
  return __uint_as_float(((u32)s) << 16);
}
__device__ __forceinline__ void gload16(const void* g, void* l) {
  __builtin_amdgcn_global_load_lds(
      (const __attribute__((address_space(1))) u32*)g,
      (__attribute__((address_space(3))) u32*)l, 16, 0, 0);
}

// ---------------------------------------------------------------------------
// R3-verified split-bf16 MFMA GEMM body (888 TF compute-regime, 0 bank
// conflicts, absmax 7.6e-6). Dual-role: blocks [0,nblk0) = GEMM1(ch),
// rest = GEMM0(ch+1). R10 measured this memory-bound: 174 MB HBM/dispatch
// at 3.5 TB/s, FETCH 92 MB vs ~40 compulsory — A panels fetched by 8 XCDs
// (linear dispatch round-robins same-by blocks across XCDs). R11 change:
// bijective XCD swizzle per sub-grid (both %8==0; sub-grid offset %8==0
// keeps hw%8 = XCD alignment) so each XCD owns a contiguous by range.
// ---------------------------------------------------------------------------
struct GArgs {
  const u16* Ah; const u16* Al;   // A hi/lo  [M][K]
  const u16* Bh; const u16* Bl;   // B^T hi/lo [N][K]
  float* C;                       // [M][NSTR]
  int K;                          // 512 (GEMM1) or 128 (GEMM0)
  int NBX;                        // 128-col panels to compute (8 or 12)
};

__global__ __launch_bounds__(256, 2)
void gemm_dual(GArgs g0, int nblk0, GArgs g1) {
  const bool first = (int)blockIdx.x < nblk0;
  const GArgs g = first ? g0 : g1;
  int bid = first ? (int)blockIdx.x : (int)blockIdx.x - nblk0;
  const int nsub = first ? nblk0 : (int)gridDim.x - nblk0;
  if ((nsub & 7) == 0) {          // bijective XCD swizzle: XCD x owns a
    const int cpx = nsub >> 3;    // contiguous logical range [x*cpx,(x+1)*cpx)
    bid = (bid & 7) * cpx + (bid >> 3);
  }
  const int K = g.K;

  __shared__ u16 sAh[4096], sAl[4096], sBh[4096], sBl[4096];

  const int bx = bid % g.NBX;
  const int by = bid / g.NBX;
  const int tid = threadIdx.x;
  const int wid = tid >> 6, lane = tid & 63;

  // staging: thread covers 16B = 8 u16; round r covers tile rows [r*64, +64)
  const int srow = tid >> 2;
  const int sw = (tid & 3) ^ ((srow >> 1) & 3);   // swizzled 16B slot
  const size_t aoff0 = (size_t)(by * 128 + srow) * K + sw * 8;
  const size_t aoff1 = aoff0 + (size_t)64 * K;
  const size_t boff0 = (size_t)(bx * 128 + srow) * K + sw * 8;
  const size_t boff1 = boff0 + (size_t)64 * K;
  const int d0 = wid * 512;          // LDS dest (u16 idx), wave-uniform
  const int d1 = 2048 + wid * 512;

  // fragment read offsets (u16 idx), swizzle-matched
  const int wm = wid >> 1, wn = wid & 1;
  const int frow = lane & 15, fsl = lane >> 4;
  int offA[4], offB[4];
#pragma unroll
  for (int i = 0; i < 4; ++i) {
    const int ra = wm * 64 + i * 16 + frow;
    offA[i] = ra * 32 + ((fsl ^ ((ra >> 1) & 3)) * 8);
    const int rb = wn * 64 + i * 16 + frow;
    offB[i] = rb * 32 + ((fsl ^ ((rb >> 1) & 3)) * 8);
  }

  f32x4 acc[4][4];
#pragma unroll
  for (int i = 0; i < 4; ++i)
#pragma unroll
    for (int j = 0; j < 4; ++j)
#pragma unroll
      for (int q = 0; q < 4; ++q) acc[i][j][q] = 0.f;

  for (int k0 = 0; k0 < K; k0 += 32) {
    __syncthreads();  // previous compute done before overwriting LDS
    gload16(g.Ah + aoff0 + k0, &sAh[d0]);
    gload16(g.Ah + aoff1 + k0, &sAh[d1]);
    gload16(g.Al + aoff0 + k0, &sAl[d0]);
    gload16(g.Al + aoff1 + k0, &sAl[d1]);
    gload16(g.Bh + boff0 + k0, &sBh[d0]);
    gload16(g.Bh + boff1 + k0, &sBh[d1]);
    gload16(g.Bl + boff0 + k0, &sBl[d0]);
    gload16(g.Bl + boff1 + k0, &sBl[d1]);
    __syncthreads();  // compiler drains vmcnt(0) before barrier

    short8 bh[4], bl[4];
#pragma unroll
    for (int j = 0; j < 4; ++j) {
      bh[j] = *(const short8*)&sBh[offB[j]];
      bl[j] = *(const short8*)&sBl[offB[j]];
    }
#pragma unroll
    for (int i = 0; i < 4; ++i) {
      const short8 ah = *(const short8*)&sAh[offA[i]];
      const short8 al = *(const short8*)&sAl[offA[i]];
#pragma unroll
      for (int j = 0; j < 4; ++j) {
        acc[i][j] = __builtin_amdgcn_mfma_f32_16x16x32_bf16(ah, bh[j], acc[i][j], 0, 0, 0);
        acc[i][j] = __builtin_amdgcn_mfma_f32_16x16x32_bf16(ah, bl[j], acc[i][j], 0, 0, 0);
        acc[i][j] = __builtin_amdgcn_mfma_f32_16x16x32_bf16(al, bh[j], acc[i][j], 0, 0, 0);
      }
    }
  }

  // epilogue: C/D layout col=lane&15, row=(lane>>4)*4+q  [R3-verified]
  const int crow0 = by * 128 + wm * 64 + (lane >> 4) * 4;
  const int ccol0 = bx * 128 + wn * 64 + (lane & 15);
#pragma unroll
  for (int i = 0; i < 4; ++i)
#pragma unroll
    for (int j = 0; j < 4; ++j) {
      float* cp = g.C + (size_t)(crow0 + i * 16) * NSTR + ccol0 + j * 16;
#pragma unroll
      for (int q = 0; q < 4; ++q) cp[(size_t)q * NSTR] = acc[i][j][q];
    }
}

// ---------------------------------------------------------------------------
// one-time input conversions
// ---------------------------------------------------------------------------
__global__ __launch_bounds__(256)
void split4_f32(const float* __restrict__ in, u16* __restrict__ hi,
                u16* __restrict__ lo, int n4) {
  const int i = blockIdx.x * 256 + threadIdx.x;
  if (i >= n4) return;
  const float4 v = ((const float4*)in)[i];
  u16 h0 = f2bf(v.x), h1 = f2bf(v.y), h2 = f2bf(v.z), h3 = f2bf(v.w);
  u16 l0 = f2bf(v.x - bf2f(h0)), l1 = f2bf(v.y - bf2f(h1));
  u16 l2 = f2bf(v.z - bf2f(h2)), l3 = f2bf(v.w - bf2f(h3));
  uint2 hp, lp;
  hp.x = (u32)h0 | ((u32)h1 << 16); hp.y = (u32)h2 | ((u32)h3 << 16);
  lp.x = (u32)l0 | ((u32)l1 << 16); lp.y = (u32)l2 | ((u32)l3 << 16);
  ((uint2*)hi)[i] = hp;
  ((uint2*)lo)[i] = lp;
}

// W[K][N] f32 -> WT hi/lo [N][K] bf16 (transposed: GEMM B-frags K-contig)
__global__ __launch_bounds__(256)
void split_w_t(const float* __restrict__ W, u16* __restrict__ Th,
               u16* __restrict__ Tl, int K, int N) {
  const int idx = blockIdx.x * 256 + threadIdx.x;
  if (idx >= K * N) return;
  const int k = idx / N, n = idx - k * N;
  const float x = W[idx];
  const u16 h = f2bf(x);
  Th[(size_t)n * K + k] = h;
  Tl[(size_t)n * K + k] = f2bf(x - bf2f(h));
}

// ---------------------------------------------------------------------------
__device__ __forceinline__ float sig(float x) { return 1.f / (1.f + __expf(-x)); }

// Layer-0 scan body: one thread per (b,h) chain over one chunk; emits h1 as
// separate hi/lo bf16 (GEMM1's A). Group-of-4 load pipeline.
__device__ __forceinline__
void scan0_body(int j, const float* __restrict__ U, const float* __restrict__ v,
                const float* __restrict__ bias, u16* __restrict__ h1h,
                u16* __restrict__ h1l, float* __restrict__ cstate, int Tc, int init) {
  const int b = j >> 9, h = j & (HID - 1);
  const float vf = v[h], vr = v[HID + h];
  const float bf = bias[h], br = bias[HID + h];

  const float* p = U + (size_t)b * NSTR + h;
  const size_t sT = (size_t)BATCH * NSTR;
  u16* ph = h1h + (size_t)b * HID + h;
  u16* pl = h1l + (size_t)b * HID + h;
  const size_t sH = (size_t)BATCH * HID;

  float c = init ? 0.f : cstate[j];
  float cu[12];
#pragma unroll
  for (int q = 0; q < 4; ++q) {
    cu[3 * q + 0] = p[q * sT];
    cu[3 * q + 1] = p[q * sT + HID];
    cu[3 * q + 2] = p[q * sT + 2 * HID];
  }
  const int NG = Tc >> 2;
  for (int g = 0; g < NG; ++g) {
    float nx[12];
    const bool has = (g + 1 < NG);
    if (has) {
      const float* pn = p + 4 * sT;
#pragma unroll
      for (int q = 0; q < 4; ++q) {
        nx[3 * q + 0] = pn[q * sT];
        nx[3 * q + 1] = pn[q * sT + HID];
        nx[3 * q + 2] = pn[q * sT + 2 * HID];
      }
    }
#pragma unroll
    for (int q = 0; q < 4; ++q) {
      const float u0 = cu[3 * q], u1 = cu[3 * q + 1], u2 = cu[3 * q + 2];
      const float f = sig(u1 + vf * c + bf);
      const float r = sig(u2 + vr * c + br);
      c = f * c + (1.f - f) * u0;
      const float hv = r * c;
      const u16 hh = f2bf(hv);
      ph[(size_t)(g * 4 + q) * sH] = hh;
      pl[(size_t)(g * 4 + q) * sH] = f2bf(hv - bf2f(hh));
    }
    p += 4 * sT;
    if (has) {
#pragma unroll
      for (int i = 0; i < 12; ++i) cu[i] = nx[i];
    }
  }
  cstate[j] = c;
}

// Layer-1 scan body: only u0/u1 needed except the single global last step.
__device__ __forceinline__
void scan1_body(int j, const float* __restrict__ U, const float* __restrict__ v,
                const float* __restrict__ bias, float* __restrict__ cstate,
                float* __restrict__ hlast, int Tc, int lastT, int init) {
  const int b = j >> 9, h = j & (HID - 1);
  const float vf = v[h], vr = v[HID + h];
  const float bf = bias[h], br = bias[HID + h];

  const float* p = U + (size_t)b * NSTR + h;
  const size_t sT = (size_t)BATCH * NSTR;

  float c = init ? 0.f : cstate[j];
  float cu[8];
#pragma unroll
  for (int q = 0; q < 4; ++q) {
    cu[2 * q + 0] = p[q * sT];
    cu[2 * q + 1] = p[q * sT + HID];
  }
  const int NG = Tc >> 2;
  for (int g = 0; g < NG; ++g) {
    float nx[8];
    const bool has = (g + 1 < NG);
    if (has) {
      const float* pn = p + 4 * sT;
#pragma unroll
      for (int q = 0; q < 4; ++q) {
        nx[2 * q + 0] = pn[q * sT];
        nx[2 * q + 1] = pn[q * sT + HID];
      }
    }
#pragma unroll
    for (int q = 0; q < 4; ++q) {
      const float u0 = cu[2 * q], u1 = cu[2 * q + 1];
      const float f = sig(u1 + vf * c + bf);
      const float cn = f * c + (1.f - f) * u0;
      if (g * 4 + q == lastT) {            // uniform; true once per sequence
        const float u2 = p[q * sT + 2 * HID];
        const float r = sig(u2 + vr * c + br);
        hlast[j] = r * cn;
      }
      c = cn;
    }
    p += 4 * sT;
    if (has) {
#pragma unroll
      for (int i = 0; i < 8; ++i) cu[i] = nx[i];
    }
  }
  cstate[j] = c;
}

// standalone layer-0 scan (chunk 0 only)
__global__ __launch_bounds__(256)
void sru_scan0(const float* __restrict__ U, const float* __restrict__ v,
               const float* __restrict__ bias, u16* __restrict__ h1h,
               u16* __restrict__ h1l, float* __restrict__ cstate, int Tc, int init) {
  scan0_body(blockIdx.x * 256 + threadIdx.x, U, v, bias, h1h, h1l, cstate, Tc, init);
}

// merged: blocks [0,256) = scan1(ch), blocks [256,512) = scan0(ch+1)
__global__ __launch_bounds__(256)
void scan_dual(const float* __restrict__ U1, const float* __restrict__ v1,
               const float* __restrict__ b1, float* __restrict__ c1,
               float* __restrict__ h2, int lastT, int init1,
               const float* __restrict__ U0n, const float* __restrict__ v0,
               const float* __restrict__ b0, u16* __restrict__ h1h,
               u16* __restrict__ h1l, float* __restrict__ c0, int Tc) {
  const int nb1 = (BATCH * HID) / 256;  // 256
  if ((int)blockIdx.x < nb1) {
    scan1_body(blockIdx.x * 256 + threadIdx.x, U1, v1, b1, c1, h2, Tc, lastT, init1);
  } else {
    scan0_body((blockIdx.x - nb1) * 256 + threadIdx.x, U0n, v0, b0, h1h, h1l, c0, Tc, 0);
  }
}

// ---------------------------------------------------------------------------
__global__ __launch_bounds__(256)
void fc_head(const float* __restrict__ h, const float* __restrict__ w,
             const float* __restrict__ bias, float* __restrict__ out) {
  const int gid = blockIdx.x * 256 + threadIdx.x;
  const int wv = gid >> 6, lane = threadIdx.x & 63;
  if (wv >= BATCH * NOUT) return;
  const int b = wv / NOUT, o = wv % NOUT;
  float s = 0.f;
#pragma unroll
  for (int k = lane; k < HID; k += 64)
    s += h[(size_t)b * HID + k] * w[(size_t)o * HID + k];
#pragma unroll
  for (int off = 32; off > 0; off >>= 1) s += __shfl_down(s, off);
  if (lane == 0) out[(size_t)b * NOUT + o] = s + bias[o];
}

// ---------------------------------------------------------------------------
extern "C" void kernel_launch(void* const* d_in, const int* in_sizes, int n_in,
                              void* d_out, int out_size, void* d_ws, size_t ws_size,
                              hipStream_t stream) {
  const float* x   = (const float*)d_in[0];
  const float* W0  = (const float*)d_in[1];
  const float* v0  = (const float*)d_in[2];
  const float* b0  = (const float*)d_in[3];
  const float* W1  = (const float*)d_in[4];
  const float* v1  = (const float*)d_in[5];
  const float* b1  = (const float*)d_in[6];
  const float* fcw = (const float*)d_in[7];
  const float* fcb = (const float*)d_in[8];
  float* out = (float*)d_out;

  const size_t nX  = (size_t)L_SEQ * BATCH * DIN;   // 8.39M
  const size_t nW0 = (size_t)DIN * NSTR;
  const size_t nW1 = (size_t)HID * NSTR;

  // largest Tc that fits: footprint(Tc) = 3*U(Tc) f32 + states + u16 arrays.
  // Tc=64 -> ~223 MB (<= 236 MB proven available in R2).
  int Tc = 64;
  for (;;) {
    size_t f32e = 3 * (size_t)Tc * BATCH * NSTR + 3 * (size_t)BATCH * HID;
    size_t u16e = 2 * nX + 4 * (size_t)Tc * BATCH * HID + 2 * nW0 + 2 * nW1;
    if (f32e * 4 + u16e * 2 + 1024 <= ws_size || Tc <= 8) break;
    Tc >>= 1;
  }
  const int NC = L_SEQ / Tc;
  const int Mc = Tc * BATCH;

  float* U1c   = (float*)d_ws;                      // [Mc][1536]
  float* U0a   = U1c + (size_t)Mc * NSTR;           // ping
  float* U0b   = U0a + (size_t)Mc * NSTR;           // pong
  float* c0    = U0b + (size_t)Mc * NSTR;
  float* c1    = c0 + (size_t)BATCH * HID;
  float* h2    = c1 + (size_t)BATCH * HID;
  u16* xs_h    = (u16*)(h2 + (size_t)BATCH * HID);
  u16* xs_l    = xs_h + nX;
  u16* h1h_a   = xs_l + nX;                         // [Mc][512] ping
  u16* h1l_a   = h1h_a + (size_t)Mc * HID;
  u16* h1h_b   = h1l_a + (size_t)Mc * HID;          // pong
  u16* h1l_b   = h1h_b + (size_t)Mc * HID;
  u16* w0t_h   = h1l_b + (size_t)Mc * HID;
  u16* w0t_l   = w0t_h + nW0;
  u16* w1t_h   = w0t_l + nW0;
  u16* w1t_l   = w1t_h + nW1;

  float* U0[2]  = {U0a, U0b};
  u16* h1h[2]   = {h1h_a, h1h_b};
  u16* h1l[2]   = {h1l_a, h1l_b};

  const int rows   = Mc / 128;                      // by range (64 at Tc=64)
  const int fcGrid = (BATCH * NOUT * 64 + 255) / 256;

  // one-time conversions
  split4_f32<<<(int)(nX / 4 + 255) / 256, 256, 0, stream>>>(x, xs_h, xs_l, (int)(nX / 4));
  split_w_t<<<(int)(nW0 + 255) / 256, 256, 0, stream>>>(W0, w0t_h, w0t_l, DIN, NSTR);
  split_w_t<<<(int)(nW1 + 255) / 256, 256, 0, stream>>>(W1, w1t_h, w1t_l, HID, NSTR);

  // GEMM0 chunk 0 -> U0[0]; scan0 chunk 0
  {
    GArgs ga = {xs_h, xs_l, w0t_h, w0t_l, U0[0], DIN, 12};
    gemm_dual<<<rows * 12, 256, 0, stream>>>(ga, rows * 12, ga);
    sru_scan0<<<(BATCH * HID) / 256, 256, 0, stream>>>(U0[0], v0, b0,
                                                       h1h[0], h1l[0], c0, Tc, 1);
  }

  for (int ch = 0; ch < NC; ++ch) {
    const bool last = (ch == NC - 1);
    const int cur = ch & 1, nxt = cur ^ 1;
    const int nbx1 = last ? 12 : 8;                 // u2-skip on non-last chunks
    const int nb0 = rows * nbx1;

    GArgs g1 = {h1h[cur], h1l[cur], w1t_h, w1t_l, U1c, HID, nbx1};
    GArgs g0n = g1;
    int nb1 = 0;
    if (!last) {
      const size_t xoff = (size_t)(ch + 1) * Mc * DIN;
      g0n = GArgs{xs_h + xoff, xs_l + xoff, w0t_h, w0t_l, U0[nxt], DIN, 12};
      nb1 = rows * 12;
    }
    gemm_dual<<<nb0 + nb1, 256, 0, stream>>>(g1, nb0, g0n);

    scan_dual<<<last ? 256 : 512, 256, 0, stream>>>(
        U1c, v1, b1, c1, h2, last ? Tc - 1 : -1, ch == 0,
        U0[nxt], v0, b0, h1h[nxt], h1l[nxt], c0, Tc);
  }
  fc_head<<<fcGrid, 256, 0, stream>>>(h2, fcw, fcb, out);
}

// Round 13
// 602.575 us; speedup vs baseline: 1.2171x; 1.0024x over previous
//
#include <hip/hip_runtime.h>
#include <math.h>

#define L_SEQ 512
#define BATCH 128
#define DIN   128
#define HID   512
#define NOUT  5
#define NSTR  1536   // C row stride (u0|u1|u2 panels)

typedef unsigned short u16;
typedef unsigned int   u32;
typedef __attribute__((ext_vector_type(8))) short short8;
typedef __attribute__((ext_vector_type(4))) float f32x4;

// ---------------------------------------------------------------------------
// bf16 split helpers (RNE).
// ---------------------------------------------------------------------------
__device__ __forceinline__ u16 f2bf(float x) {
  u32 u = __float_as_uint(x);
  return (u16)((u + 0x7fffu + ((u >> 16) & 1u)) >> 16);
}
__device__ __forceinline__ float bf2f(u16 s) {
  return __uint_as_float(((u32)s) << 16);
}
__device__ __forceinline__ void gload16(const void* g, void* l) {
  __builtin_amdgcn_global_load_lds(
      (const __attribute__((address_space(1))) u32*)g,
      (__attribute__((address_space(3))) u32*)l, 16, 0, 0);
}

// ---------------------------------------------------------------------------
// R3-verified split-bf16 MFMA GEMM body. R11 added per-sub-grid XCD swizzle
// (FETCH 92->27 MB). R12: __launch_bounds__(256,4) — occupancy was 22%
// (2 blocks/CU); LDS 32KB allows 4, VGPR 76 <= 128 cap. m114: this
// structure's throughput comes from cross-block overlap of the barrier
// drain; more resident blocks -> more overlap.
// Dual-role: blocks [0,nblk0) = GEMM1(ch), rest = GEMM0(ch+1).
// ---------------------------------------------------------------------------
struct GArgs {
  const u16* Ah; const u16* Al;   // A hi/lo  [M][K]
  const u16* Bh; const u16* Bl;   // B^T hi/lo [N][K]
  float* C;                       // [M][NSTR]
  int K;                          // 512 (GEMM1) or 128 (GEMM0)
  int NBX;                        // 128-col panels to compute (8 or 12)
};

__global__ __launch_bounds__(256, 4)
void gemm_dual(GArgs g0, int nblk0, GArgs g1) {
  const bool first = (int)blockIdx.x < nblk0;
  const GArgs g = first ? g0 : g1;
  int bid = first ? (int)blockIdx.x : (int)blockIdx.x - nblk0;
  const int nsub = first ? nblk0 : (int)gridDim.x - nblk0;
  if ((nsub & 7) == 0) {          // bijective XCD swizzle: XCD x owns a
    const int cpx = nsub >> 3;    // contiguous logical range [x*cpx,(x+1)*cpx)
    bid = (bid & 7) * cpx + (bid >> 3);
  }
  const int K = g.K;

  __shared__ u16 sAh[4096], sAl[4096], sBh[4096], sBl[4096];

  const int bx = bid % g.NBX;
  const int by = bid / g.NBX;
  const int tid = threadIdx.x;
  const int wid = tid >> 6, lane = tid & 63;

  // staging: thread covers 16B = 8 u16; round r covers tile rows [r*64, +64)
  const int srow = tid >> 2;
  const int sw = (tid & 3) ^ ((srow >> 1) & 3);   // swizzled 16B slot
  const size_t aoff0 = (size_t)(by * 128 + srow) * K + sw * 8;
  const size_t aoff1 = aoff0 + (size_t)64 * K;
  const size_t boff0 = (size_t)(bx * 128 + srow) * K + sw * 8;
  const size_t boff1 = boff0 + (size_t)64 * K;
  const int d0 = wid * 512;          // LDS dest (u16 idx), wave-uniform
  const int d1 = 2048 + wid * 512;

  // fragment read offsets (u16 idx), swizzle-matched
  const int wm = wid >> 1, wn = wid & 1;
  const int frow = lane & 15, fsl = lane >> 4;
  int offA[4], offB[4];
#pragma unroll
  for (int i = 0; i < 4; ++i) {
    const int ra = wm * 64 + i * 16 + frow;
    offA[i] = ra * 32 + ((fsl ^ ((ra >> 1) & 3)) * 8);
    const int rb = wn * 64 + i * 16 + frow;
    offB[i] = rb * 32 + ((fsl ^ ((rb >> 1) & 3)) * 8);
  }

  f32x4 acc[4][4];
#pragma unroll
  for (int i = 0; i < 4; ++i)
#pragma unroll
    for (int j = 0; j < 4; ++j)
#pragma unroll
      for (int q = 0; q < 4; ++q) acc[i][j][q] = 0.f;

  for (int k0 = 0; k0 < K; k0 += 32) {
    __syncthreads();  // previous compute done before overwriting LDS
    gload16(g.Ah + aoff0 + k0, &sAh[d0]);
    gload16(g.Ah + aoff1 + k0, &sAh[d1]);
    gload16(g.Al + aoff0 + k0, &sAl[d0]);
    gload16(g.Al + aoff1 + k0, &sAl[d1]);
    gload16(g.Bh + boff0 + k0, &sBh[d0]);
    gload16(g.Bh + boff1 + k0, &sBh[d1]);
    gload16(g.Bl + boff0 + k0, &sBl[d0]);
    gload16(g.Bl + boff1 + k0, &sBl[d1]);
    __syncthreads();  // compiler drains vmcnt(0) before barrier

    short8 bh[4], bl[4];
#pragma unroll
    for (int j = 0; j < 4; ++j) {
      bh[j] = *(const short8*)&sBh[offB[j]];
      bl[j] = *(const short8*)&sBl[offB[j]];
    }
#pragma unroll
    for (int i = 0; i < 4; ++i) {
      const short8 ah = *(const short8*)&sAh[offA[i]];
      const short8 al = *(const short8*)&sAl[offA[i]];
#pragma unroll
      for (int j = 0; j < 4; ++j) {
        acc[i][j] = __builtin_amdgcn_mfma_f32_16x16x32_bf16(ah, bh[j], acc[i][j], 0, 0, 0);
        acc[i][j] = __builtin_amdgcn_mfma_f32_16x16x32_bf16(ah, bl[j], acc[i][j], 0, 0, 0);
        acc[i][j] = __builtin_amdgcn_mfma_f32_16x16x32_bf16(al, bh[j], acc[i][j], 0, 0, 0);
      }
    }
  }

  // epilogue: C/D layout col=lane&15, row=(lane>>4)*4+q  [R3-verified]
  const int crow0 = by * 128 + wm * 64 + (lane >> 4) * 4;
  const int ccol0 = bx * 128 + wn * 64 + (lane & 15);
#pragma unroll
  for (int i = 0; i < 4; ++i)
#pragma unroll
    for (int j = 0; j < 4; ++j) {
      float* cp = g.C + (size_t)(crow0 + i * 16) * NSTR + ccol0 + j * 16;
#pragma unroll
      for (int q = 0; q < 4; ++q) cp[(size_t)q * NSTR] = acc[i][j][q];
    }
}

// ---------------------------------------------------------------------------
// one-time input conversions
// ---------------------------------------------------------------------------
__global__ __launch_bounds__(256)
void split4_f32(const float* __restrict__ in, u16* __restrict__ hi,
                u16* __restrict__ lo, int n4) {
  const int i = blockIdx.x * 256 + threadIdx.x;
  if (i >= n4) return;
  const float4 v = ((const float4*)in)[i];
  u16 h0 = f2bf(v.x), h1 = f2bf(v.y), h2 = f2bf(v.z), h3 = f2bf(v.w);
  u16 l0 = f2bf(v.x - bf2f(h0)), l1 = f2bf(v.y - bf2f(h1));
  u16 l2 = f2bf(v.z - bf2f(h2)), l3 = f2bf(v.w - bf2f(h3));
  uint2 hp, lp;
  hp.x = (u32)h0 | ((u32)h1 << 16); hp.y = (u32)h2 | ((u32)h3 << 16);
  lp.x = (u32)l0 | ((u32)l1 << 16); lp.y = (u32)l2 | ((u32)l3 << 16);
  ((uint2*)hi)[i] = hp;
  ((uint2*)lo)[i] = lp;
}

// W[K][N] f32 -> WT hi/lo [N][K] bf16 (transposed: GEMM B-frags K-contig)
__global__ __launch_bounds__(256)
void split_w_t(const float* __restrict__ W, u16* __restrict__ Th,
               u16* __restrict__ Tl, int K, int N) {
  const int idx = blockIdx.x * 256 + threadIdx.x;
  if (idx >= K * N) return;
  const int k = idx / N, n = idx - k * N;
  const float x = W[idx];
  const u16 h = f2bf(x);
  Th[(size_t)n * K + k] = h;
  Tl[(size_t)n * K + k] = f2bf(x - bf2f(h));
}

// ---------------------------------------------------------------------------
__device__ __forceinline__ float sig(float x) { return 1.f / (1.f + __expf(-x)); }

// Layer-0 scan body: one thread per (b,h) chain over one chunk; emits h1 as
// separate hi/lo bf16 (GEMM1's A). Group-of-8 load pipeline (R12: was 4 —
// 24 outstanding loads vs 12, scans were 68% of achievable BW).
__device__ __forceinline__
void scan0_body(int j, const float* __restrict__ U, const float* __restrict__ v,
                const float* __restrict__ bias, u16* __restrict__ h1h,
                u16* __restrict__ h1l, float* __restrict__ cstate, int Tc, int init) {
  const int b = j >> 9, h = j & (HID - 1);
  const float vf = v[h], vr = v[HID + h];
  const float bf = bias[h], br = bias[HID + h];

  const float* p = U + (size_t)b * NSTR + h;
  const size_t sT = (size_t)BATCH * NSTR;
  u16* ph = h1h + (size_t)b * HID + h;
  u16* pl = h1l + (size_t)b * HID + h;
  const size_t sH = (size_t)BATCH * HID;

  float c = init ? 0.f : cstate[j];
  float cu[24];
#pragma unroll
  for (int q = 0; q < 8; ++q) {
    cu[3 * q + 0] = p[q * sT];
    cu[3 * q + 1] = p[q * sT + HID];
    cu[3 * q + 2] = p[q * sT + 2 * HID];
  }
  const int NG = Tc >> 3;
  for (int g = 0; g < NG; ++g) {
    float nx[24];
    const bool has = (g + 1 < NG);
    if (has) {
      const float* pn = p + 8 * sT;
#pragma unroll
      for (int q = 0; q < 8; ++q) {
        nx[3 * q + 0] = pn[q * sT];
        nx[3 * q + 1] = pn[q * sT + HID];
        nx[3 * q + 2] = pn[q * sT + 2 * HID];
      }
    }
#pragma unroll
    for (int q = 0; q < 8; ++q) {
      const float u0 = cu[3 * q], u1 = cu[3 * q + 1], u2 = cu[3 * q + 2];
      const float f = sig(u1 + vf * c + bf);
      const float r = sig(u2 + vr * c + br);
      c = f * c + (1.f - f) * u0;
      const float hv = r * c;
      const u16 hh = f2bf(hv);
      ph[(size_t)(g * 8 + q) * sH] = hh;
      pl[(size_t)(g * 8 + q) * sH] = f2bf(hv - bf2f(hh));
    }
    p += 8 * sT;
    if (has) {
#pragma unroll
      for (int i = 0; i < 24; ++i) cu[i] = nx[i];
    }
  }
  cstate[j] = c;
}

// Layer-1 scan body: only u0/u1 needed except the single global last step.
__device__ __forceinline__
void scan1_body(int j, const float* __restrict__ U, const float* __restrict__ v,
                const float* __restrict__ bias, float* __restrict__ cstate,
                float* __restrict__ hlast, int Tc, int lastT, int init) {
  const int b = j >> 9, h = j & (HID - 1);
  const float vf = v[h], vr = v[HID + h];
  const float bf = bias[h], br = bias[HID + h];

  const float* p = U + (size_t)b * NSTR + h;
  const size_t sT = (size_t)BATCH * NSTR;

  float c = init ? 0.f : cstate[j];
  float cu[16];
#pragma unroll
  for (int q = 0; q < 8; ++q) {
    cu[2 * q + 0] = p[q * sT];
    cu[2 * q + 1] = p[q * sT + HID];
  }
  const int NG = Tc >> 3;
  for (int g = 0; g < NG; ++g) {
    float nx[16];
    const bool has = (g + 1 < NG);
    if (has) {
      const float* pn = p + 8 * sT;
#pragma unroll
      for (int q = 0; q < 8; ++q) {
        nx[2 * q + 0] = pn[q * sT];
        nx[2 * q + 1] = pn[q * sT + HID];
      }
    }
#pragma unroll
    for (int q = 0; q < 8; ++q) {
      const float u0 = cu[2 * q], u1 = cu[2 * q + 1];
      const float f = sig(u1 + vf * c + bf);
      const float cn = f * c + (1.f - f) * u0;
      if (g * 8 + q == lastT) {            // uniform; true once per sequence
        const float u2 = p[q * sT + 2 * HID];
        const float r = sig(u2 + vr * c + br);
        hlast[j] = r * cn;
      }
      c = cn;
    }
    p += 8 * sT;
    if (has) {
#pragma unroll
      for (int i = 0; i < 16; ++i) cu[i] = nx[i];
    }
  }
  cstate[j] = c;
}

// standalone layer-0 scan (chunk 0 only)
__global__ __launch_bounds__(256)
void sru_scan0(const float* __restrict__ U, const float* __restrict__ v,
               const float* __restrict__ bias, u16* __restrict__ h1h,
               u16* __restrict__ h1l, float* __restrict__ cstate, int Tc, int init) {
  scan0_body(blockIdx.x * 256 + threadIdx.x, U, v, bias, h1h, h1l, cstate, Tc, init);
}

// merged: blocks [0,256) = scan1(ch), blocks [256,512) = scan0(ch+1)
__global__ __launch_bounds__(256)
void scan_dual(const float* __restrict__ U1, const float* __restrict__ v1,
               const float* __restrict__ b1, float* __restrict__ c1,
               float* __restrict__ h2, int lastT, int init1,
               const float* __restrict__ U0n, const float* __restrict__ v0,
               const float* __restrict__ b0, u16* __restrict__ h1h,
               u16* __restrict__ h1l, float* __restrict__ c0, int Tc) {
  const int nb1 = (BATCH * HID) / 256;  // 256
  if ((int)blockIdx.x < nb1) {
    scan1_body(blockIdx.x * 256 + threadIdx.x, U1, v1, b1, c1, h2, Tc, lastT, init1);
  } else {
    scan0_body((blockIdx.x - nb1) * 256 + threadIdx.x, U0n, v0, b0, h1h, h1l, c0, Tc, 0);
  }
}

// ---------------------------------------------------------------------------
__global__ __launch_bounds__(256)
void fc_head(const float* __restrict__ h, const float* __restrict__ w,
             const float* __restrict__ bias, float* __restrict__ out) {
  const int gid = blockIdx.x * 256 + threadIdx.x;
  const int wv = gid >> 6, lane = threadIdx.x & 63;
  if (wv >= BATCH * NOUT) return;
  const int b = wv / NOUT, o = wv % NOUT;
  float s = 0.f;
#pragma unroll
  for (int k = lane; k < HID; k += 64)
    s += h[(size_t)b * HID + k] * w[(size_t)o * HID + k];
#pragma unroll
  for (int off = 32; off > 0; off >>= 1) s += __shfl_down(s, off);
  if (lane == 0) out[(size_t)b * NOUT + o] = s + bias[o];
}

// ---------------------------------------------------------------------------
extern "C" void kernel_launch(void* const* d_in, const int* in_sizes, int n_in,
                              void* d_out, int out_size, void* d_ws, size_t ws_size,
                              hipStream_t stream) {
  const float* x   = (const float*)d_in[0];
  const float* W0  = (const float*)d_in[1];
  const float* v0  = (const float*)d_in[2];
  const float* b0  = (const float*)d_in[3];
  const float* W1  = (const float*)d_in[4];
  const float* v1  = (const float*)d_in[5];
  const float* b1  = (const float*)d_in[6];
  const float* fcw = (const float*)d_in[7];
  const float* fcb = (const float*)d_in[8];
  float* out = (float*)d_out;

  const size_t nX  = (size_t)L_SEQ * BATCH * DIN;   // 8.39M
  const size_t nW0 = (size_t)DIN * NSTR;
  const size_t nW1 = (size_t)HID * NSTR;

  // largest Tc that fits: footprint(Tc) = 3*U(Tc) f32 + states + u16 arrays.
  // Tc=64 -> ~223 MB (<= 236 MB proven available in R2).
  int Tc = 64;
  for (;;) {
    size_t f32e = 3 * (size_t)Tc * BATCH * NSTR + 3 * (size_t)BATCH * HID;
    size_t u16e = 2 * nX + 4 * (size_t)Tc * BATCH * HID + 2 * nW0 + 2 * nW1;
    if (f32e * 4 + u16e * 2 + 1024 <= ws_size || Tc <= 8) break;
    Tc >>= 1;
  }
  const int NC = L_SEQ / Tc;
  const int Mc = Tc * BATCH;

  float* U1c   = (float*)d_ws;                      // [Mc][1536]
  float* U0a   = U1c + (size_t)Mc * NSTR;           // ping
  float* U0b   = U0a + (size_t)Mc * NSTR;           // pong
  float* c0    = U0b + (size_t)Mc * NSTR;
  float* c1    = c0 + (size_t)BATCH * HID;
  float* h2    = c1 + (size_t)BATCH * HID;
  u16* xs_h    = (u16*)(h2 + (size_t)BATCH * HID);
  u16* xs_l    = xs_h + nX;
  u16* h1h_a   = xs_l + nX;                         // [Mc][512] ping
  u16* h1l_a   = h1h_a + (size_t)Mc * HID;
  u16* h1h_b   = h1l_a + (size_t)Mc * HID;          // pong
  u16* h1l_b   = h1h_b + (size_t)Mc * HID;
  u16* w0t_h   = h1l_b + (size_t)Mc * HID;
  u16* w0t_l   = w0t_h + nW0;
  u16* w1t_h   = w0t_l + nW0;
  u16* w1t_l   = w1t_h + nW1;

  float* U0[2]  = {U0a, U0b};
  u16* h1h[2]   = {h1h_a, h1h_b};
  u16* h1l[2]   = {h1l_a, h1l_b};

  const int rows   = Mc / 128;                      // by range (64 at Tc=64)
  const int fcGrid = (BATCH * NOUT * 64 + 255) / 256;

  // one-time conversions
  split4_f32<<<(int)(nX / 4 + 255) / 256, 256, 0, stream>>>(x, xs_h, xs_l, (int)(nX / 4));
  split_w_t<<<(int)(nW0 + 255) / 256, 256, 0, stream>>>(W0, w0t_h, w0t_l, DIN, NSTR);
  split_w_t<<<(int)(nW1 + 255) / 256, 256, 0, stream>>>(W1, w1t_h, w1t_l, HID, NSTR);

  // GEMM0 chunk 0 -> U0[0]; scan0 chunk 0
  {
    GArgs ga = {xs_h, xs_l, w0t_h, w0t_l, U0[0], DIN, 12};
    gemm_dual<<<rows * 12, 256, 0, stream>>>(ga, rows * 12, ga);
    sru_scan0<<<(BATCH * HID) / 256, 256, 0, stream>>>(U0[0], v0, b0,
                                                       h1h[0], h1l[0], c0, Tc, 1);
  }

  for (int ch = 0; ch < NC; ++ch) {
    const bool last = (ch == NC - 1);
    const int cur = ch & 1, nxt = cur ^ 1;
    const int nbx1 = last ? 12 : 8;                 // u2-skip on non-last chunks
    const int nb0 = rows * nbx1;

    GArgs g1 = {h1h[cur], h1l[cur], w1t_h, w1t_l, U1c, HID, nbx1};
    GArgs g0n = g1;
    int nb1 = 0;
    if (!last) {
      const size_t xoff = (size_t)(ch + 1) * Mc * DIN;
      g0n = GArgs{xs_h + xoff, xs_l + xoff, w0t_h, w0t_l, U0[nxt], DIN, 12};
      nb1 = rows * 12;
    }
    gemm_dual<<<nb0 + nb1, 256, 0, stream>>>(g1, nb0, g0n);

    scan_dual<<<last ? 256 : 512, 256, 0, stream>>>(
        U1c, v1, b1, c1, h2, last ? Tc - 1 : -1, ch == 0,
        U0[nxt], v0, b0, h1h[nxt], h1l[nxt], c0, Tc);
  }
  fc_head<<<fcGrid, 256, 0, stream>>>(h2, fcw, fcb, out);
}